// Round 1
// baseline (149.418 us; speedup 1.0000x reference)
//
#include <hip/hip_runtime.h>

#define N_SAMP 256
#define IN_F   1024
#define OUT_F  128
#define KDIM   32
#define JTOT   (OUT_F * KDIM)   // 4096
#define OUT_ROW (IN_F + OUT_F)  // 1152

// ---------------------------------------------------------------------------
// Kernel 1: copy x into out[:, :1024] and init o_b slots to -1.0
// (-1 cancels the self-term exp(0)=1 that the dist kernel will add)
// ---------------------------------------------------------------------------
__global__ __launch_bounds__(256) void copy_init_kernel(const float* __restrict__ x,
                                                        float* __restrict__ out) {
    int n = blockIdx.x;
    int t = threadIdx.x;
    const float4* xrow = reinterpret_cast<const float4*>(x + (size_t)n * IN_F);
    float4* orow = reinterpret_cast<float4*>(out + (size_t)n * OUT_ROW);
    orow[t] = xrow[t];                     // 256 threads x float4 = 1024 floats
    if (t < OUT_F) out[(size_t)n * OUT_ROW + IN_F + t] = -1.0f;
}

// ---------------------------------------------------------------------------
// Kernel 2: fp32 GEMM  M[256][4096] = x[256][1024] @ T[1024][4096]
// BM=64, BN=64, BK=16, 256 threads, 4x4 micro-tile per thread.
// ---------------------------------------------------------------------------
#define BM 64
#define BN 64
#define BK 16
#define AS_STRIDE 68   // padded to dodge store bank conflicts; 68*4B % 16 == 0

__global__ __launch_bounds__(256) void gemm_kernel(const float* __restrict__ x,
                                                   const float* __restrict__ T,
                                                   float* __restrict__ M) {
    __shared__ float As[BK][AS_STRIDE];  // x tile, transposed: As[k][row]
    __shared__ float Bs[BK][BN];         // T tile: Bs[k][col]

    const int jb = blockIdx.x * BN;      // output col base (0..4032)
    const int nb = blockIdx.y * BM;      // output row base (0..192)
    const int t  = threadIdx.x;
    const int tx = t & 15;               // micro-tile col group
    const int ty = t >> 4;               // micro-tile row group

    float acc[4][4] = {};

    for (int k0 = 0; k0 < IN_F; k0 += BK) {
        // stage x tile: 64 rows x 16 k  (1 float4 per thread, stored transposed)
        {
            int row = t >> 2;
            int cg  = (t & 3) * 4;
            float4 v = *reinterpret_cast<const float4*>(&x[(size_t)(nb + row) * IN_F + k0 + cg]);
            As[cg + 0][row] = v.x;
            As[cg + 1][row] = v.y;
            As[cg + 2][row] = v.z;
            As[cg + 3][row] = v.w;
        }
        // stage T tile: 16 k x 64 cols (1 float4 per thread, direct)
        {
            int r  = t >> 4;
            int cg = (t & 15) * 4;
            float4 v = *reinterpret_cast<const float4*>(&T[(size_t)(k0 + r) * JTOT + jb + cg]);
            *reinterpret_cast<float4*>(&Bs[r][cg]) = v;
        }
        __syncthreads();

#pragma unroll
        for (int kk = 0; kk < BK; ++kk) {
            float4 av = *reinterpret_cast<const float4*>(&As[kk][ty * 4]);
            float4 bv = *reinterpret_cast<const float4*>(&Bs[kk][tx * 4]);
            float a[4] = {av.x, av.y, av.z, av.w};
            float b[4] = {bv.x, bv.y, bv.z, bv.w};
#pragma unroll
            for (int i = 0; i < 4; ++i)
#pragma unroll
                for (int j = 0; j < 4; ++j)
                    acc[i][j] += a[i] * b[j];
        }
        __syncthreads();
    }

#pragma unroll
    for (int i = 0; i < 4; ++i) {
        int n = nb + ty * 4 + i;
        float4 v = make_float4(acc[i][0], acc[i][1], acc[i][2], acc[i][3]);
        *reinterpret_cast<float4*>(&M[(size_t)n * JTOT + jb + tx * 4]) = v;
    }
}

// ---------------------------------------------------------------------------
// Kernel 3: pairwise L1 distance over k, exp(-d), sum over m.
// Block = (o, m-chunk of 64). 256 threads = one per n.
// Own row in VGPRs; m-chunk rows in LDS, read as wave-uniform broadcasts.
// ---------------------------------------------------------------------------
__global__ __launch_bounds__(256) void dist_kernel(const float* __restrict__ M,
                                                   float* __restrict__ out) {
    __shared__ float Mo[64][KDIM];       // 8 KiB

    const int o     = blockIdx.x >> 2;   // 0..127
    const int chunk = blockIdx.x & 3;    // 0..3
    const int t     = threadIdx.x;       // n = 0..255

    // own row -> 32 VGPRs
    float r[KDIM];
    const float4* mrow = reinterpret_cast<const float4*>(&M[(size_t)t * JTOT + o * KDIM]);
#pragma unroll
    for (int f = 0; f < 8; ++f) {
        float4 v = mrow[f];
        r[f * 4 + 0] = v.x; r[f * 4 + 1] = v.y;
        r[f * 4 + 2] = v.z; r[f * 4 + 3] = v.w;
    }

    // stage the 64 m-chunk rows (two passes of 32 rows; contiguous float4s)
    const int mbase = chunk * 64;
    {
        int row = t >> 3;       // 0..31
        int f4  = t & 7;        // 0..7
        *reinterpret_cast<float4*>(&Mo[row][f4 * 4]) =
            *reinterpret_cast<const float4*>(&M[(size_t)(mbase + row) * JTOT + o * KDIM + f4 * 4]);
        *reinterpret_cast<float4*>(&Mo[row + 32][f4 * 4]) =
            *reinterpret_cast<const float4*>(&M[(size_t)(mbase + row + 32) * JTOT + o * KDIM + f4 * 4]);
    }
    __syncthreads();

    float acc = 0.f;
    for (int m = 0; m < 64; ++m) {
        float d = 0.f;
#pragma unroll
        for (int k = 0; k < KDIM; ++k)
            d += fabsf(r[k] - Mo[m][k]);
        acc += __expf(-d);
    }

    atomicAdd(&out[(size_t)t * OUT_ROW + IN_F + o], acc);
}

// ---------------------------------------------------------------------------
extern "C" void kernel_launch(void* const* d_in, const int* in_sizes, int n_in,
                              void* d_out, int out_size, void* d_ws, size_t ws_size,
                              hipStream_t stream) {
    const float* x = (const float*)d_in[0];   // [256,1024]
    const float* T = (const float*)d_in[1];   // [1024,128,32]
    float* out = (float*)d_out;               // [256,1152]
    float* M   = (float*)d_ws;                // [256,4096] = 4 MiB scratch

    // 1. copy x + init o_b to -1 (must precede dist atomics; stream-ordered)
    copy_init_kernel<<<N_SAMP, 256, 0, stream>>>(x, out);

    // 2. M = x @ T
    dim3 ggrid(JTOT / BN, N_SAMP / BM);       // (64, 4)
    gemm_kernel<<<ggrid, 256, 0, stream>>>(x, T, M);

    // 3. pairwise exp(-L1) accumulation
    dist_kernel<<<OUT_F * 4, 256, 0, stream>>>(M, out);
}